// Round 2
// baseline (489.045 us; speedup 1.0000x reference)
//
#include <hip/hip_runtime.h>

// N=100000 nodes, M=800000 edges, F_IN=64, F_E=16, H=64, T_NODE=2, T_EDGE=3.
// score == softmax over singleton axis == 1.0 exactly, so h3/h4/num are dead:
//   out[n] = h1[n] + sum_{e: dst=n} ( h2[src_e] + ef_e . W5[t_e] + b5[t_e] )
//
// R2: counting-sort edges by dst (hist -> scan -> scatter), then one wave per
// dst sums its edges and writes out once. No float atomics. h2 stored bf16.

__device__ __forceinline__ float b2f(unsigned short u) {
    union { unsigned v; float f; } x; x.v = ((unsigned)u) << 16; return x.f;
}
__device__ __forceinline__ unsigned short f2b(float f) {
    union { float f; unsigned v; } x; x.f = f;
    unsigned u = x.v;
    unsigned r = (u + 0x7FFFu + ((u >> 16) & 1u)) >> 16;
    return (unsigned short)r;
}

__device__ __forceinline__ void fma4(float4& a, float s, const float4& w) {
    a.x = fmaf(s, w.x, a.x);
    a.y = fmaf(s, w.y, a.y);
    a.z = fmaf(s, w.z, a.z);
    a.w = fmaf(s, w.w, a.w);
}

// ---------------- bucket nodes by type + histogram edge_dst ----------------
__global__ __launch_bounds__(256) void bucket_hist_kernel(
    const int* __restrict__ node_type, const int* __restrict__ edst,
    int* __restrict__ perm, int* __restrict__ cnt, int* __restrict__ cntE,
    int N, int M)
{
    int tid = blockIdx.x * 256 + threadIdx.x;
    int lane = threadIdx.x & 63;
    bool act = tid < N;
    int t = act ? node_type[tid] : -1;
    unsigned long long m0 = __ballot(act && (t == 0));
    unsigned long long m1 = __ballot(act && (t > 0));
    unsigned long long lt = (lane == 0) ? 0ull : ((~0ull) >> (64 - lane));
    if (act) {
        if (t == 0) {
            int cw = __popcll(m0), pre = __popcll(m0 & lt);
            int ldr = __ffsll(m0) - 1;
            int base = 0;
            if (lane == ldr) base = atomicAdd(&cnt[0], cw);
            base = __shfl(base, ldr);
            perm[base + pre] = tid;
        } else {
            int cw = __popcll(m1), pre = __popcll(m1 & lt);
            int ldr = __ffsll(m1) - 1;
            int base = 0;
            if (lane == ldr) base = atomicAdd(&cnt[1], cw);
            base = __shfl(base, ldr);
            perm[N - 1 - (base + pre)] = tid;
        }
    }
    if (tid < M) atomicAdd(&cntE[edst[tid]], 1);
}

// ---------------- scan: 1024 elems per block ----------------
__global__ __launch_bounds__(256) void scan1_kernel(
    const int* __restrict__ cntE, int* __restrict__ rowptr,
    int* __restrict__ blockSum)
{
    __shared__ int ss[256];
    int tid = threadIdx.x;
    int base = blockIdx.x * 1024 + tid * 4;
    int4 v = *(const int4*)&cntE[base];
    int s = v.x + v.y + v.z + v.w;
    ss[tid] = s;
    __syncthreads();
    int run = s;
    for (int off = 1; off < 256; off <<= 1) {
        int tmp = (tid >= off) ? ss[tid - off] : 0;
        __syncthreads();
        run += tmp;
        ss[tid] = run;
        __syncthreads();
    }
    int ex = run - s;
    int4 o;
    o.x = ex; o.y = ex + v.x; o.z = o.y + v.y; o.w = o.z + v.z;
    *(int4*)&rowptr[base] = o;
    if (tid == 255) blockSum[blockIdx.x] = run;
}

__global__ __launch_bounds__(128) void scan2_kernel(
    const int* __restrict__ blockSum, int* __restrict__ blockOff, int nb)
{
    __shared__ int ss[128];
    int tid = threadIdx.x;
    int s = (tid < nb) ? blockSum[tid] : 0;
    ss[tid] = s;
    __syncthreads();
    int run = s;
    for (int off = 1; off < 128; off <<= 1) {
        int tmp = (tid >= off) ? ss[tid - off] : 0;
        __syncthreads();
        run += tmp;
        ss[tid] = run;
        __syncthreads();
    }
    blockOff[tid] = run - s;
}

__global__ __launch_bounds__(256) void finalize_kernel(
    int* __restrict__ rowptr, int* __restrict__ cursor,
    const int* __restrict__ blockOff, int N)
{
    int i = blockIdx.x * 256 + threadIdx.x;
    if (i < N) {
        int v = rowptr[i] + blockOff[i >> 10];
        rowptr[i] = v;
        cursor[i] = v;
    }
}

// ---------------- scatter edges into dst-sorted records ----------------
__global__ __launch_bounds__(256) void scatter_kernel(
    const int* __restrict__ esrc, const int* __restrict__ edst,
    const int* __restrict__ etype, int* __restrict__ cursor,
    int2* __restrict__ rec, int M)
{
    int e = blockIdx.x * 256 + threadIdx.x;
    if (e >= M) return;
    int d = edst[e];
    int pos = atomicAdd(&cursor[d], 1);
    rec[pos] = make_int2(esrc[e] | (etype[e] << 20), e);
}

// ---------------- node projection: h1 -> out, h2(bf16) -> ws ----------------
__global__ __launch_bounds__(256) void node_gemm_kernel(
    const float* __restrict__ x, const int* __restrict__ perm,
    const int* __restrict__ cnt,
    const float* __restrict__ W1, const float* __restrict__ b1,
    const float* __restrict__ W2, const float* __restrict__ b2,
    float* __restrict__ out, unsigned short* __restrict__ h2b,
    int N, int nb)
{
    __shared__ float sx[64][128];
    __shared__ float sW1[64][64];
    __shared__ float sW2[64][64];

    int tid = threadIdx.x;
    int c0 = cnt[0];
    int side = (blockIdx.x >= (unsigned)nb) ? 1 : 0;
    int b = blockIdx.x - side * nb;
    int rowbase = side ? (c0 + b * 128) : (b * 128);
    int rowend  = side ? N : c0;
    if (rowbase >= rowend) return;

    const float* W1t = W1 + side * 4096;
    const float* W2t = W2 + side * 4096;
#pragma unroll
    for (int k = 0; k < 4; ++k) {
        int idx = k * 1024 + tid * 4;
        *(float4*)&sW1[0][idx] = *(const float4*)&W1t[idx];
        *(float4*)&sW2[0][idx] = *(const float4*)&W2t[idx];
    }

    int fr = (tid & 15) * 4;
    int ir = tid >> 4;
#pragma unroll
    for (int it = 0; it < 8; ++it) {
        int i = it * 16 + ir;
        int r = rowbase + i;
        float4 v = make_float4(0.f, 0.f, 0.f, 0.f);
        if (r < rowend) {
            int n = perm[r];
            v = *(const float4*)&x[n * 64 + fr];
        }
        sx[fr + 0][i] = v.x;
        sx[fr + 1][i] = v.y;
        sx[fr + 2][i] = v.z;
        sx[fr + 3][i] = v.w;
    }
    __syncthreads();

    int hg = tid & 15;
    int ng = tid >> 4;
    float4 a1[8], a2[8];
#pragma unroll
    for (int j = 0; j < 8; ++j) {
        a1[j] = make_float4(0.f, 0.f, 0.f, 0.f);
        a2[j] = make_float4(0.f, 0.f, 0.f, 0.f);
    }

#pragma unroll 4
    for (int f = 0; f < 64; ++f) {
        float4 w1 = *(const float4*)&sW1[f][hg * 4];
        float4 w2 = *(const float4*)&sW2[f][hg * 4];
        float4 xa = *(const float4*)&sx[f][ng * 8];
        float4 xb = *(const float4*)&sx[f][ng * 8 + 4];
        fma4(a1[0], xa.x, w1); fma4(a2[0], xa.x, w2);
        fma4(a1[1], xa.y, w1); fma4(a2[1], xa.y, w2);
        fma4(a1[2], xa.z, w1); fma4(a2[2], xa.z, w2);
        fma4(a1[3], xa.w, w1); fma4(a2[3], xa.w, w2);
        fma4(a1[4], xb.x, w1); fma4(a2[4], xb.x, w2);
        fma4(a1[5], xb.y, w1); fma4(a2[5], xb.y, w2);
        fma4(a1[6], xb.z, w1); fma4(a2[6], xb.z, w2);
        fma4(a1[7], xb.w, w1); fma4(a2[7], xb.w, w2);
    }

    float4 bb1 = *(const float4*)&b1[side * 64 + hg * 4];
    float4 bb2 = *(const float4*)&b2[side * 64 + hg * 4];
#pragma unroll
    for (int j = 0; j < 8; ++j) {
        int r = rowbase + ng * 8 + j;
        if (r < rowend) {
            int n = perm[r];
            float4 o1 = make_float4(a1[j].x + bb1.x, a1[j].y + bb1.y,
                                    a1[j].z + bb1.z, a1[j].w + bb1.w);
            *(float4*)&out[n * 64 + hg * 4] = o1;
            ushort4 p;
            p.x = f2b(a2[j].x + bb2.x);
            p.y = f2b(a2[j].y + bb2.y);
            p.z = f2b(a2[j].z + bb2.z);
            p.w = f2b(a2[j].w + bb2.w);
            *(ushort4*)&h2b[n * 64 + hg * 4] = p;
        }
    }
}

// ---------------- gather: one wave per dst node, lane = h ----------------
__device__ __forceinline__ float dot16(const float* w, float b, const float* e) {
    float s0 = b, s1 = 0.f;
#pragma unroll
    for (int f = 0; f < 16; f += 2) {
        s0 = fmaf(e[f], w[f], s0);
        s1 = fmaf(e[f + 1], w[f + 1], s1);
    }
    return s0 + s1;
}

__global__ __launch_bounds__(256) void gather_kernel(
    const float* __restrict__ ef, const int2* __restrict__ rec,
    const int* __restrict__ rowptr, const int* __restrict__ cursor,
    const float* __restrict__ W5, const float* __restrict__ b5,
    const unsigned short* __restrict__ h2b, float* __restrict__ out, int N)
{
    int lane = threadIdx.x & 63;
    int wid = threadIdx.x >> 6;
    int d = blockIdx.x * 4 + wid;
    if (d >= N) return;

    float w50[16], w51[16], w52[16];
#pragma unroll
    for (int f = 0; f < 16; ++f) {
        w50[f] = W5[f * 64 + lane];
        w51[f] = W5[1024 + f * 64 + lane];
        w52[f] = W5[2048 + f * 64 + lane];
    }
    float b50 = b5[lane], b51 = b5[64 + lane], b52 = b5[128 + lane];

    int beg = rowptr[d];
    int end = cursor[d];

    float acc0 = 0.f, acc1 = 0.f;
    int i = beg;
    for (; i + 1 < end; i += 2) {
        int2 r0 = rec[i];
        int2 r1 = rec[i + 1];
        int s0 = r0.x & 0xFFFFF, t0 = r0.x >> 20;
        int s1 = r1.x & 0xFFFFF, t1 = r1.x >> 20;
        float hv0 = b2f(h2b[s0 * 64 + lane]);
        float hv1 = b2f(h2b[s1 * 64 + lane]);
        const float* efp0 = ef + (size_t)r0.y * 16;
        const float* efp1 = ef + (size_t)r1.y * 16;
        float e0[16], e1[16];
#pragma unroll
        for (int f = 0; f < 16; ++f) { e0[f] = efp0[f]; e1[f] = efp1[f]; }
        float a0 = (t0 == 0) ? dot16(w50, b50, e0)
                 : (t0 == 1) ? dot16(w51, b51, e0) : dot16(w52, b52, e0);
        float a1v = (t1 == 0) ? dot16(w50, b50, e1)
                  : (t1 == 1) ? dot16(w51, b51, e1) : dot16(w52, b52, e1);
        acc0 += a0 + hv0;
        acc1 += a1v + hv1;
    }
    if (i < end) {
        int2 r0 = rec[i];
        int s0 = r0.x & 0xFFFFF, t0 = r0.x >> 20;
        float hv0 = b2f(h2b[s0 * 64 + lane]);
        const float* efp0 = ef + (size_t)r0.y * 16;
        float e0[16];
#pragma unroll
        for (int f = 0; f < 16; ++f) e0[f] = efp0[f];
        float a0 = (t0 == 0) ? dot16(w50, b50, e0)
                 : (t0 == 1) ? dot16(w51, b51, e0) : dot16(w52, b52, e0);
        acc0 += a0 + hv0;
    }
    out[d * 64 + lane] += acc0 + acc1;
}

extern "C" void kernel_launch(void* const* d_in, const int* in_sizes, int n_in,
                              void* d_out, int out_size, void* d_ws, size_t ws_size,
                              hipStream_t stream) {
    const float* x  = (const float*)d_in[0];
    const float* ef = (const float*)d_in[1];
    const int* nt   = (const int*)d_in[2];
    const int* es   = (const int*)d_in[3];
    const int* ed   = (const int*)d_in[4];
    const int* et   = (const int*)d_in[5];
    const float* W1 = (const float*)d_in[6];
    const float* b1 = (const float*)d_in[7];
    const float* W2 = (const float*)d_in[8];
    const float* b2 = (const float*)d_in[9];
    // d_in[10..13] = W3,b3,W4,b4 dead (score == 1.0)
    const float* W5 = (const float*)d_in[14];
    const float* b5 = (const float*)d_in[15];

    int N = in_sizes[2];
    int M = in_sizes[3];
    int NB1 = (N + 1023) / 1024;      // scan blocks
    int Npad = NB1 * 1024;

    char* w = (char*)d_ws;
    size_t off = 0;
    unsigned short* h2b = (unsigned short*)(w + off); off += (size_t)N * 64 * 2;     // 12.8 MB
    off = (off + 255) & ~(size_t)255;
    int2* rec    = (int2*)(w + off); off += (size_t)M * 8;                            // 6.4 MB
    int* perm    = (int*)(w + off);  off += (size_t)N * 4;
    off = (off + 255) & ~(size_t)255;
    int* rowptr  = (int*)(w + off);  off += (size_t)Npad * 4;
    int* cursor  = (int*)(w + off);  off += (size_t)Npad * 4;
    off = (off + 255) & ~(size_t)255;
    int* cnt     = (int*)(w + off);  off += 16;                 // 2 used, pad to 16B
    int* cntE    = (int*)(w + off);  off += (size_t)Npad * 4;   // memset with cnt
    int* blockSum= (int*)(w + off);  off += 128 * 4;
    int* blockOff= (int*)(w + off);  off += 128 * 4;

    float* out = (float*)d_out;

    // zero cnt + cntE in one shot (contiguous)
    hipMemsetAsync(cnt, 0, 16 + (size_t)Npad * 4, stream);

    int gbMN = (M + 255) / 256;
    bucket_hist_kernel<<<gbMN, 256, 0, stream>>>(nt, ed, perm, cnt, cntE, N, M);

    int nb = (N + 127) / 128;
    node_gemm_kernel<<<2 * nb, 256, 0, stream>>>(x, perm, cnt, W1, b1, W2, b2,
                                                 out, h2b, N, nb);

    scan1_kernel<<<NB1, 256, 0, stream>>>(cntE, rowptr, blockSum);
    scan2_kernel<<<1, 128, 0, stream>>>(blockSum, blockOff, NB1);
    finalize_kernel<<<(N + 255) / 256, 256, 0, stream>>>(rowptr, cursor, blockOff, N);

    scatter_kernel<<<gbMN, 256, 0, stream>>>(es, ed, et, cursor, rec, M);

    gather_kernel<<<(N + 3) / 4, 256, 0, stream>>>(ef, rec, rowptr, cursor,
                                                   W5, b5, h2b, out, N);
}

// Round 4
// 346.867 us; speedup vs baseline: 1.4099x; 1.4099x over previous
//
#include <hip/hip_runtime.h>

// N=100000 nodes, M=800000 edges, F_IN=64, F_E=16, H=64, T_NODE=2, T_EDGE=3.
// score == softmax over singleton axis == 1.0 exactly, so h3/h4/num are dead:
//   out[n] = h1[n] + sum_{e: dst=n} ( h2[src_e] + ef_e . W5[t_e] + b5[t_e] )
//
// R4 = R3 + fix: finalize_kernel must also finalize rowptr[N] (gather reads
// rowptr[d+1]; rowptr[N] was left un-offset -> node N-1 lost its edge sum).

__device__ __forceinline__ float b2f(unsigned short u) {
    union { unsigned v; float f; } x; x.v = ((unsigned)u) << 16; return x.f;
}
__device__ __forceinline__ unsigned short f2b(float f) {
    union { float f; unsigned v; } x; x.f = f;
    unsigned u = x.v;
    unsigned r = (u + 0x7FFFu + ((u >> 16) & 1u)) >> 16;
    return (unsigned short)r;
}

__device__ __forceinline__ void fma4(float4& a, float s, const float4& w) {
    a.x = fmaf(s, w.x, a.x);
    a.y = fmaf(s, w.y, a.y);
    a.z = fmaf(s, w.z, a.z);
    a.w = fmaf(s, w.w, a.w);
}

// ---------------- bucket nodes by type + histogram edge_dst ----------------
__global__ __launch_bounds__(256) void bucket_hist_kernel(
    const int* __restrict__ node_type, const int* __restrict__ edst,
    int* __restrict__ perm, int* __restrict__ cnt, int* __restrict__ cntE,
    int N, int M)
{
    int tid = blockIdx.x * 256 + threadIdx.x;
    int lane = threadIdx.x & 63;
    bool act = tid < N;
    int t = act ? node_type[tid] : -1;
    unsigned long long m0 = __ballot(act && (t == 0));
    unsigned long long m1 = __ballot(act && (t > 0));
    unsigned long long lt = (lane == 0) ? 0ull : ((~0ull) >> (64 - lane));
    if (act) {
        if (t == 0) {
            int cw = __popcll(m0), pre = __popcll(m0 & lt);
            int ldr = __ffsll(m0) - 1;
            int base = 0;
            if (lane == ldr) base = atomicAdd(&cnt[0], cw);
            base = __shfl(base, ldr);
            perm[base + pre] = tid;
        } else {
            int cw = __popcll(m1), pre = __popcll(m1 & lt);
            int ldr = __ffsll(m1) - 1;
            int base = 0;
            if (lane == ldr) base = atomicAdd(&cnt[1], cw);
            base = __shfl(base, ldr);
            perm[N - 1 - (base + pre)] = tid;
        }
    }
    if (tid < M) atomicAdd(&cntE[edst[tid]], 1);
}

// ---------------- scan: 1024 elems per block ----------------
__global__ __launch_bounds__(256) void scan1_kernel(
    const int* __restrict__ cntE, int* __restrict__ rowptr,
    int* __restrict__ blockSum)
{
    __shared__ int ss[256];
    int tid = threadIdx.x;
    int base = blockIdx.x * 1024 + tid * 4;
    int4 v = *(const int4*)&cntE[base];
    int s = v.x + v.y + v.z + v.w;
    ss[tid] = s;
    __syncthreads();
    int run = s;
    for (int off = 1; off < 256; off <<= 1) {
        int tmp = (tid >= off) ? ss[tid - off] : 0;
        __syncthreads();
        run += tmp;
        ss[tid] = run;
        __syncthreads();
    }
    int ex = run - s;
    int4 o;
    o.x = ex; o.y = ex + v.x; o.z = o.y + v.y; o.w = o.z + v.z;
    *(int4*)&rowptr[base] = o;
    if (tid == 255) blockSum[blockIdx.x] = run;
}

__global__ __launch_bounds__(128) void scan2_kernel(
    const int* __restrict__ blockSum, int* __restrict__ blockOff, int nb)
{
    __shared__ int ss[128];
    int tid = threadIdx.x;
    int s = (tid < nb) ? blockSum[tid] : 0;
    ss[tid] = s;
    __syncthreads();
    int run = s;
    for (int off = 1; off < 128; off <<= 1) {
        int tmp = (tid >= off) ? ss[tid - off] : 0;
        __syncthreads();
        run += tmp;
        ss[tid] = run;
        __syncthreads();
    }
    blockOff[tid] = run - s;
}

__global__ __launch_bounds__(256) void finalize_kernel(
    int* __restrict__ rowptr, int* __restrict__ cursor,
    const int* __restrict__ blockOff, int N)
{
    int i = blockIdx.x * 256 + threadIdx.x;
    if (i <= N) {   // include rowptr[N] = M (gather reads rowptr[d+1])
        int v = rowptr[i] + blockOff[i >> 10];
        rowptr[i] = v;
        cursor[i] = v;
    }
}

// ---------------- scatter edges into dst-sorted records ----------------
__global__ __launch_bounds__(256) void scatter_kernel(
    const int* __restrict__ esrc, const int* __restrict__ edst,
    const int* __restrict__ etype, int* __restrict__ cursor,
    int2* __restrict__ rec, int M)
{
    int e = blockIdx.x * 256 + threadIdx.x;
    if (e >= M) return;
    int d = edst[e];
    int pos = atomicAdd(&cursor[d], 1);
    rec[pos] = make_int2(esrc[e] | (etype[e] << 20), e);
}

// ---------------- node projection: h1 -> out, h2(bf16) -> ws ----------------
__global__ __launch_bounds__(256) void node_gemm_kernel(
    const float* __restrict__ x, const int* __restrict__ perm,
    const int* __restrict__ cnt,
    const float* __restrict__ W1, const float* __restrict__ b1,
    const float* __restrict__ W2, const float* __restrict__ b2,
    float* __restrict__ out, unsigned short* __restrict__ h2b,
    int N, int nb)
{
    __shared__ float sx[64][128];
    __shared__ float sW1[64][64];
    __shared__ float sW2[64][64];

    int tid = threadIdx.x;
    int c0 = cnt[0];
    int side = (blockIdx.x >= (unsigned)nb) ? 1 : 0;
    int b = blockIdx.x - side * nb;
    int rowbase = side ? (c0 + b * 128) : (b * 128);
    int rowend  = side ? N : c0;
    if (rowbase >= rowend) return;

    const float* W1t = W1 + side * 4096;
    const float* W2t = W2 + side * 4096;
#pragma unroll
    for (int k = 0; k < 4; ++k) {
        int idx = k * 1024 + tid * 4;
        *(float4*)&sW1[0][idx] = *(const float4*)&W1t[idx];
        *(float4*)&sW2[0][idx] = *(const float4*)&W2t[idx];
    }

    int fr = (tid & 15) * 4;
    int ir = tid >> 4;
#pragma unroll
    for (int it = 0; it < 8; ++it) {
        int i = it * 16 + ir;
        int r = rowbase + i;
        float4 v = make_float4(0.f, 0.f, 0.f, 0.f);
        if (r < rowend) {
            int n = perm[r];
            v = *(const float4*)&x[n * 64 + fr];
        }
        sx[fr + 0][i] = v.x;
        sx[fr + 1][i] = v.y;
        sx[fr + 2][i] = v.z;
        sx[fr + 3][i] = v.w;
    }
    __syncthreads();

    int hg = tid & 15;
    int ng = tid >> 4;
    float4 a1[8], a2[8];
#pragma unroll
    for (int j = 0; j < 8; ++j) {
        a1[j] = make_float4(0.f, 0.f, 0.f, 0.f);
        a2[j] = make_float4(0.f, 0.f, 0.f, 0.f);
    }

#pragma unroll 4
    for (int f = 0; f < 64; ++f) {
        float4 w1 = *(const float4*)&sW1[f][hg * 4];
        float4 w2 = *(const float4*)&sW2[f][hg * 4];
        float4 xa = *(const float4*)&sx[f][ng * 8];
        float4 xb = *(const float4*)&sx[f][ng * 8 + 4];
        fma4(a1[0], xa.x, w1); fma4(a2[0], xa.x, w2);
        fma4(a1[1], xa.y, w1); fma4(a2[1], xa.y, w2);
        fma4(a1[2], xa.z, w1); fma4(a2[2], xa.z, w2);
        fma4(a1[3], xa.w, w1); fma4(a2[3], xa.w, w2);
        fma4(a1[4], xb.x, w1); fma4(a2[4], xb.x, w2);
        fma4(a1[5], xb.y, w1); fma4(a2[5], xb.y, w2);
        fma4(a1[6], xb.z, w1); fma4(a2[6], xb.z, w2);
        fma4(a1[7], xb.w, w1); fma4(a2[7], xb.w, w2);
    }

    float4 bb1 = *(const float4*)&b1[side * 64 + hg * 4];
    float4 bb2 = *(const float4*)&b2[side * 64 + hg * 4];
#pragma unroll
    for (int j = 0; j < 8; ++j) {
        int r = rowbase + ng * 8 + j;
        if (r < rowend) {
            int n = perm[r];
            float4 o1 = make_float4(a1[j].x + bb1.x, a1[j].y + bb1.y,
                                    a1[j].z + bb1.z, a1[j].w + bb1.w);
            *(float4*)&out[n * 64 + hg * 4] = o1;
            ushort4 p;
            p.x = f2b(a2[j].x + bb2.x);
            p.y = f2b(a2[j].y + bb2.y);
            p.z = f2b(a2[j].z + bb2.z);
            p.w = f2b(a2[j].w + bb2.w);
            *(ushort4*)&h2b[n * 64 + hg * 4] = p;
        }
    }
}

// ---------------- gather: one wave per dst node ----------------
// lane roles during edge loop:
//   all lanes:    accH += h2b[src][lane]
//   lanes 0..47:  accS += (etype == lane>>4) ? ef[edge][lane&15] : 0
//   lanes 48..50: accS += (etype == lane-48) ? 1 : 0   (type counts)
// epilogue: out[d] += accH + sum_j G[j]*Wcat[j][lane]  (51x64 matvec via LDS)
__global__ __launch_bounds__(256) void gather_kernel(
    const float* __restrict__ ef, const int2* __restrict__ rec,
    const int* __restrict__ rowptr,
    const float* __restrict__ W5, const float* __restrict__ b5,
    const unsigned short* __restrict__ h2b, float* __restrict__ out, int N)
{
    __shared__ float sW[3072 + 192];   // W5 then b5
    __shared__ float sG[4][64];

    int tid = threadIdx.x;
    // stage W5 (768 float4) + b5 (48 float4)
    for (int k = tid; k < 816; k += 256) {
        ((float4*)sW)[k] = (k < 768) ? ((const float4*)W5)[k]
                                     : ((const float4*)b5)[k - 768];
    }
    __syncthreads();

    int lane = tid & 63;
    int wid = __builtin_amdgcn_readfirstlane(tid >> 6);
    int d = blockIdx.x * 4 + wid;
    bool active = d < N;
    int dd = active ? d : 0;
    int beg = active ? rowptr[dd] : 0;
    int end = active ? rowptr[dd + 1] : 0;

    int myt = (lane < 48) ? (lane >> 4) : (lane - 48);
    int myf = lane & 15;
    float accH = 0.f, accS = 0.f;

    for (int i = beg; i < end; i += 4) {
        // over-reads past segment end stay inside ws and are masked by nrem
        int2 r0 = rec[i];
        int2 r1 = rec[i + 1];
        int2 r2 = rec[i + 2];
        int2 r3 = rec[i + 3];
        int s0 = r0.x & 0xFFFFF, t0 = (unsigned)r0.x >> 20;
        int s1 = r1.x & 0xFFFFF, t1 = (unsigned)r1.x >> 20;
        int s2 = r2.x & 0xFFFFF, t2 = (unsigned)r2.x >> 20;
        int s3 = r3.x & 0xFFFFF, t3 = (unsigned)r3.x >> 20;
        float h0 = b2f(h2b[(size_t)s0 * 64 + lane]);
        float h1 = b2f(h2b[(size_t)s1 * 64 + lane]);
        float h2v = b2f(h2b[(size_t)s2 * 64 + lane]);
        float h3 = b2f(h2b[(size_t)s3 * 64 + lane]);
        float e0 = ef[(size_t)r0.y * 16 + myf];
        float e1 = ef[(size_t)r1.y * 16 + myf];
        float e2 = ef[(size_t)r2.y * 16 + myf];
        float e3 = ef[(size_t)r3.y * 16 + myf];
        int nrem = end - i;
        float v0 = (lane < 48) ? e0 : 1.0f;
        float v1 = (lane < 48) ? e1 : 1.0f;
        float v2 = (lane < 48) ? e2 : 1.0f;
        float v3 = (lane < 48) ? e3 : 1.0f;
        accH += h0;
        accS += ((int)t0 == myt) ? v0 : 0.f;
        accH += (1 < nrem) ? h1 : 0.f;
        accS += ((1 < nrem) && ((int)t1 == myt)) ? v1 : 0.f;
        accH += (2 < nrem) ? h2v : 0.f;
        accS += ((2 < nrem) && ((int)t2 == myt)) ? v2 : 0.f;
        accH += (3 < nrem) ? h3 : 0.f;
        accS += ((3 < nrem) && ((int)t3 == myt)) ? v3 : 0.f;
    }

    // per-wave 51x64 matvec from LDS (DS ops are in-order within a wave)
    sG[wid][lane] = accS;
    float r = accH;
    const float* g = sG[wid];
#pragma unroll
    for (int j = 0; j < 48; ++j)
        r = fmaf(g[j], sW[j * 64 + lane], r);
#pragma unroll
    for (int t = 0; t < 3; ++t)
        r = fmaf(g[48 + t], sW[3072 + t * 64 + lane], r);

    if (active)
        out[(size_t)d * 64 + lane] += r;
}

extern "C" void kernel_launch(void* const* d_in, const int* in_sizes, int n_in,
                              void* d_out, int out_size, void* d_ws, size_t ws_size,
                              hipStream_t stream) {
    const float* x  = (const float*)d_in[0];
    const float* ef = (const float*)d_in[1];
    const int* nt   = (const int*)d_in[2];
    const int* es   = (const int*)d_in[3];
    const int* ed   = (const int*)d_in[4];
    const int* et   = (const int*)d_in[5];
    const float* W1 = (const float*)d_in[6];
    const float* b1 = (const float*)d_in[7];
    const float* W2 = (const float*)d_in[8];
    const float* b2 = (const float*)d_in[9];
    // d_in[10..13] = W3,b3,W4,b4 dead (score == 1.0)
    const float* W5 = (const float*)d_in[14];
    const float* b5 = (const float*)d_in[15];

    int N = in_sizes[2];
    int M = in_sizes[3];
    int NB1 = (N + 1023) / 1024;
    int Npad = NB1 * 1024;

    char* w = (char*)d_ws;
    size_t off = 0;
    unsigned short* h2b = (unsigned short*)(w + off); off += (size_t)N * 64 * 2;
    off = (off + 255) & ~(size_t)255;
    int2* rec    = (int2*)(w + off); off += (size_t)M * 8;
    int* perm    = (int*)(w + off);  off += (size_t)N * 4;
    off = (off + 255) & ~(size_t)255;
    int* rowptr  = (int*)(w + off);  off += (size_t)Npad * 4;
    int* cursor  = (int*)(w + off);  off += (size_t)Npad * 4;
    off = (off + 255) & ~(size_t)255;
    int* cnt     = (int*)(w + off);  off += 16;
    int* cntE    = (int*)(w + off);  off += (size_t)Npad * 4;
    int* blockSum= (int*)(w + off);  off += 128 * 4;
    int* blockOff= (int*)(w + off);  off += 128 * 4;

    float* out = (float*)d_out;

    hipMemsetAsync(cnt, 0, 16 + (size_t)Npad * 4, stream);

    int gbMN = (M + 255) / 256;
    bucket_hist_kernel<<<gbMN, 256, 0, stream>>>(nt, ed, perm, cnt, cntE, N, M);

    int nb = (N + 127) / 128;
    node_gemm_kernel<<<2 * nb, 256, 0, stream>>>(x, perm, cnt, W1, b1, W2, b2,
                                                 out, h2b, N, nb);

    scan1_kernel<<<NB1, 256, 0, stream>>>(cntE, rowptr, blockSum);
    scan2_kernel<<<1, 128, 0, stream>>>(blockSum, blockOff, NB1);
    finalize_kernel<<<(N + 255) / 256, 256, 0, stream>>>(rowptr, cursor, blockOff, N);

    scatter_kernel<<<gbMN, 256, 0, stream>>>(es, ed, et, cursor, rec, M);

    gather_kernel<<<(N + 3) / 4, 256, 0, stream>>>(ef, rec, rowptr,
                                                   W5, b5, h2b, out, N);
}

// Round 5
// 309.988 us; speedup vs baseline: 1.5776x; 1.1190x over previous
//
#include <hip/hip_runtime.h>

// N=100000 nodes, M=800000 edges, F_IN=64, F_E=16, H=64, T_NODE=2, T_EDGE=3.
// score == softmax over singleton axis == 1.0 exactly, so h3/h4/num are dead:
//   out[n] = h1[n] + sum_{e: dst=n} ( h2[src_e] + ef_e . W5[t_e] + b5[t_e] )
//
// R5: (1) node projection rewritten as MFMA bf16 16x16x32 (128x64 tile);
//     (2) gemm + scatter horizontally fused into one kernel (independent
//         bottlenecks: MFMA/LDS vs random atomics) so they overlap;
//     (3) scan2 folded into finalize (block-uniform scalar prefix).

typedef __attribute__((ext_vector_type(8))) short short8;
typedef __attribute__((ext_vector_type(4))) float f32x4;

__device__ __forceinline__ float b2f(unsigned short u) {
    union { unsigned v; float f; } x; x.v = ((unsigned)u) << 16; return x.f;
}
__device__ __forceinline__ unsigned short f2b(float f) {
    union { float f; unsigned v; } x; x.f = f;
    unsigned u = x.v;
    unsigned r = (u + 0x7FFFu + ((u >> 16) & 1u)) >> 16;
    return (unsigned short)r;
}

// ---------------- bucket nodes by type + histogram edge_dst ----------------
__global__ __launch_bounds__(256) void bucket_hist_kernel(
    const int* __restrict__ node_type, const int* __restrict__ edst,
    int* __restrict__ perm, int* __restrict__ cnt, int* __restrict__ cntE,
    int N, int M)
{
    int tid = blockIdx.x * 256 + threadIdx.x;
    int lane = threadIdx.x & 63;
    bool act = tid < N;
    int t = act ? node_type[tid] : -1;
    unsigned long long m0 = __ballot(act && (t == 0));
    unsigned long long m1 = __ballot(act && (t > 0));
    unsigned long long lt = (lane == 0) ? 0ull : ((~0ull) >> (64 - lane));
    if (act) {
        if (t == 0) {
            int cw = __popcll(m0), pre = __popcll(m0 & lt);
            int ldr = __ffsll(m0) - 1;
            int base = 0;
            if (lane == ldr) base = atomicAdd(&cnt[0], cw);
            base = __shfl(base, ldr);
            perm[base + pre] = tid;
        } else {
            int cw = __popcll(m1), pre = __popcll(m1 & lt);
            int ldr = __ffsll(m1) - 1;
            int base = 0;
            if (lane == ldr) base = atomicAdd(&cnt[1], cw);
            base = __shfl(base, ldr);
            perm[N - 1 - (base + pre)] = tid;
        }
    }
    if (tid < M) atomicAdd(&cntE[edst[tid]], 1);
}

// ---------------- scan: 1024 elems per block ----------------
__global__ __launch_bounds__(256) void scan1_kernel(
    const int* __restrict__ cntE, int* __restrict__ rowptr,
    int* __restrict__ blockSum)
{
    __shared__ int ss[256];
    int tid = threadIdx.x;
    int base = blockIdx.x * 1024 + tid * 4;
    int4 v = *(const int4*)&cntE[base];
    int s = v.x + v.y + v.z + v.w;
    ss[tid] = s;
    __syncthreads();
    int run = s;
    for (int off = 1; off < 256; off <<= 1) {
        int tmp = (tid >= off) ? ss[tid - off] : 0;
        __syncthreads();
        run += tmp;
        ss[tid] = run;
        __syncthreads();
    }
    int ex = run - s;
    int4 o;
    o.x = ex; o.y = ex + v.x; o.z = o.y + v.y; o.w = o.z + v.z;
    *(int4*)&rowptr[base] = o;
    if (tid == 255) blockSum[blockIdx.x] = run;
}

// scan2 + finalize fused: each block covers 256 indices, all within ONE
// 1024-chunk (256 | 1024), so the needed blockSum prefix is block-uniform.
__global__ __launch_bounds__(256) void finalize2_kernel(
    int* __restrict__ rowptr, int* __restrict__ cursor,
    const int* __restrict__ blockSum, int N)
{
    int i = blockIdx.x * 256 + threadIdx.x;
    int sb = blockIdx.x >> 2;           // == i >> 10 for all threads
    int off = 0;
    for (int j = 0; j < sb; ++j) off += blockSum[j];   // uniform -> s_loads
    if (i <= N) {   // include rowptr[N] = M (gather reads rowptr[d+1])
        int v = rowptr[i] + off;
        rowptr[i] = v;
        cursor[i] = v;
    }
}

// ---------------- fused: MFMA node projection || edge scatter ----------------
// Blocks [0, 2*nb): gemm path (128 nodes x 64 h, bf16 MFMA, h1->out h2->ws).
// Blocks [2*nb, ...): scatter path (256 edges -> dst-sorted rec via cursor).
__global__ __launch_bounds__(256) void fused_gemm_scatter_kernel(
    const float* __restrict__ x, const int* __restrict__ perm,
    const int* __restrict__ cnt,
    const float* __restrict__ W1, const float* __restrict__ b1,
    const float* __restrict__ W2, const float* __restrict__ b2,
    float* __restrict__ out, unsigned short* __restrict__ h2b,
    const int* __restrict__ esrc, const int* __restrict__ edst,
    const int* __restrict__ etype, int* __restrict__ cursor,
    int2* __restrict__ rec,
    int N, int M, int nb)
{
    // 72 = 64 + 8 pad: row stride 144 B -> bank advance 4/row -> 2-way (free)
    __shared__ __align__(16) unsigned short sx[128 * 72];    // 18 KB
    __shared__ __align__(16) unsigned short sw[2][64 * 72];  // 18 KB

    int tid = threadIdx.x;

    if (blockIdx.x >= (unsigned)(2 * nb)) {
        // ---------------- scatter path ----------------
        int e = (blockIdx.x - 2 * nb) * 256 + tid;
        if (e < M) {
            int d = edst[e];
            int pos = atomicAdd(&cursor[d], 1);
            rec[pos] = make_int2(esrc[e] | (etype[e] << 20), e);
        }
        return;
    }

    // ---------------- gemm path ----------------
    int c0 = cnt[0];
    int side = (blockIdx.x >= (unsigned)nb) ? 1 : 0;
    int b = blockIdx.x - side * nb;
    int rowbase = side ? (c0 + b * 128) : (b * 128);
    int rowend  = side ? N : c0;
    if (rowbase >= rowend) return;

    const float* W1t = W1 + side * 4096;   // [k][n] fp32
    const float* W2t = W2 + side * 4096;

    // stage W -> sw[mm][n*72 + k] (bf16, transposed)
#pragma unroll
    for (int j = 0; j < 4; ++j) {
        int k  = (tid >> 4) + j * 16;
        int n4 = (tid & 15) * 4;
        float4 w1v = *(const float4*)&W1t[k * 64 + n4];
        float4 w2v = *(const float4*)&W2t[k * 64 + n4];
        sw[0][(n4 + 0) * 72 + k] = f2b(w1v.x);
        sw[0][(n4 + 1) * 72 + k] = f2b(w1v.y);
        sw[0][(n4 + 2) * 72 + k] = f2b(w1v.z);
        sw[0][(n4 + 3) * 72 + k] = f2b(w1v.w);
        sw[1][(n4 + 0) * 72 + k] = f2b(w2v.x);
        sw[1][(n4 + 1) * 72 + k] = f2b(w2v.y);
        sw[1][(n4 + 2) * 72 + k] = f2b(w2v.z);
        sw[1][(n4 + 3) * 72 + k] = f2b(w2v.w);
    }

    // stage x tile -> sx[m*72 + k] (bf16)
    int fr = (tid & 15) * 4;
    int ir = tid >> 4;
#pragma unroll
    for (int it = 0; it < 8; ++it) {
        int i = it * 16 + ir;
        int r = rowbase + i;
        float4 v = make_float4(0.f, 0.f, 0.f, 0.f);
        if (r < rowend) {
            int n = perm[r];
            v = *(const float4*)&x[n * 64 + fr];
        }
        ushort4 p;
        p.x = f2b(v.x); p.y = f2b(v.y); p.z = f2b(v.z); p.w = f2b(v.w);
        *(ushort4*)&sx[i * 72 + fr] = p;
    }
    __syncthreads();

    int lane = tid & 63;
    int wid  = tid >> 6;
    int q    = lane >> 4;     // quad
    int cc   = lane & 15;     // col within 16 (and A-row within 16)
    int m0   = wid * 32;      // wave's row base in tile

    f32x4 acc[2][2][4];
#pragma unroll
    for (int mm = 0; mm < 2; ++mm)
#pragma unroll
        for (int s = 0; s < 2; ++s)
#pragma unroll
            for (int t = 0; t < 4; ++t)
                acc[mm][s][t] = (f32x4){0.f, 0.f, 0.f, 0.f};

#pragma unroll
    for (int k0 = 0; k0 < 64; k0 += 32) {
        int ko = k0 + q * 8;
        short8 af[2];
        af[0] = *(short8*)&sx[(m0 + cc) * 72 + ko];
        af[1] = *(short8*)&sx[(m0 + 16 + cc) * 72 + ko];
        short8 bf[2][4];
#pragma unroll
        for (int mm = 0; mm < 2; ++mm)
#pragma unroll
            for (int t = 0; t < 4; ++t)
                bf[mm][t] = *(short8*)&sw[mm][(t * 16 + cc) * 72 + ko];
#pragma unroll
        for (int mm = 0; mm < 2; ++mm)
#pragma unroll
            for (int s = 0; s < 2; ++s)
#pragma unroll
                for (int t = 0; t < 4; ++t)
                    acc[mm][s][t] = __builtin_amdgcn_mfma_f32_16x16x32_bf16(
                        af[s], bf[mm][t], acc[mm][s][t], 0, 0, 0);
    }

    float bia1[4], bia2[4];
#pragma unroll
    for (int t = 0; t < 4; ++t) {
        bia1[t] = b1[side * 64 + t * 16 + cc];
        bia2[t] = b2[side * 64 + t * 16 + cc];
    }

    // C/D layout: col = lane&15, row = quad*4 + reg
#pragma unroll
    for (int s = 0; s < 2; ++s)
#pragma unroll
        for (int reg = 0; reg < 4; ++reg) {
            int rl = m0 + s * 16 + q * 4 + reg;
            int r = rowbase + rl;
            if (r < rowend) {
                int n = perm[r];
#pragma unroll
                for (int t = 0; t < 4; ++t) {
                    out[n * 64 + t * 16 + cc] = acc[0][s][t][reg] + bia1[t];
                    h2b[n * 64 + t * 16 + cc] = f2b(acc[1][s][t][reg] + bia2[t]);
                }
            }
        }
}

// ---------------- gather: one wave per dst node ----------------
__global__ __launch_bounds__(256) void gather_kernel(
    const float* __restrict__ ef, const int2* __restrict__ rec,
    const int* __restrict__ rowptr,
    const float* __restrict__ W5, const float* __restrict__ b5,
    const unsigned short* __restrict__ h2b, float* __restrict__ out, int N)
{
    __shared__ float sW[3072 + 192];   // W5 then b5
    __shared__ float sG[4][64];

    int tid = threadIdx.x;
    for (int k = tid; k < 816; k += 256) {
        ((float4*)sW)[k] = (k < 768) ? ((const float4*)W5)[k]
                                     : ((const float4*)b5)[k - 768];
    }
    __syncthreads();

    int lane = tid & 63;
    int wid = __builtin_amdgcn_readfirstlane(tid >> 6);
    int d = blockIdx.x * 4 + wid;
    bool active = d < N;
    int dd = active ? d : 0;
    int beg = active ? rowptr[dd] : 0;
    int end = active ? rowptr[dd + 1] : 0;

    int myt = (lane < 48) ? (lane >> 4) : (lane - 48);
    int myf = lane & 15;
    float accH = 0.f, accS = 0.f;

    for (int i = beg; i < end; i += 4) {
        int2 r0 = rec[i];
        int2 r1 = rec[i + 1];
        int2 r2 = rec[i + 2];
        int2 r3 = rec[i + 3];
        int s0 = r0.x & 0xFFFFF, t0 = (unsigned)r0.x >> 20;
        int s1 = r1.x & 0xFFFFF, t1 = (unsigned)r1.x >> 20;
        int s2 = r2.x & 0xFFFFF, t2 = (unsigned)r2.x >> 20;
        int s3 = r3.x & 0xFFFFF, t3 = (unsigned)r3.x >> 20;
        float h0 = b2f(h2b[(size_t)s0 * 64 + lane]);
        float h1 = b2f(h2b[(size_t)s1 * 64 + lane]);
        float h2v = b2f(h2b[(size_t)s2 * 64 + lane]);
        float h3 = b2f(h2b[(size_t)s3 * 64 + lane]);
        float e0 = ef[(size_t)r0.y * 16 + myf];
        float e1 = ef[(size_t)r1.y * 16 + myf];
        float e2 = ef[(size_t)r2.y * 16 + myf];
        float e3 = ef[(size_t)r3.y * 16 + myf];
        int nrem = end - i;
        float v0 = (lane < 48) ? e0 : 1.0f;
        float v1 = (lane < 48) ? e1 : 1.0f;
        float v2 = (lane < 48) ? e2 : 1.0f;
        float v3 = (lane < 48) ? e3 : 1.0f;
        accH += h0;
        accS += ((int)t0 == myt) ? v0 : 0.f;
        accH += (1 < nrem) ? h1 : 0.f;
        accS += ((1 < nrem) && ((int)t1 == myt)) ? v1 : 0.f;
        accH += (2 < nrem) ? h2v : 0.f;
        accS += ((2 < nrem) && ((int)t2 == myt)) ? v2 : 0.f;
        accH += (3 < nrem) ? h3 : 0.f;
        accS += ((3 < nrem) && ((int)t3 == myt)) ? v3 : 0.f;
    }

    sG[wid][lane] = accS;
    float r = accH;
    const float* g = sG[wid];
#pragma unroll
    for (int j = 0; j < 48; ++j)
        r = fmaf(g[j], sW[j * 64 + lane], r);
#pragma unroll
    for (int t = 0; t < 3; ++t)
        r = fmaf(g[48 + t], sW[3072 + t * 64 + lane], r);

    if (active)
        out[(size_t)d * 64 + lane] += r;
}

extern "C" void kernel_launch(void* const* d_in, const int* in_sizes, int n_in,
                              void* d_out, int out_size, void* d_ws, size_t ws_size,
                              hipStream_t stream) {
    const float* x  = (const float*)d_in[0];
    const float* ef = (const float*)d_in[1];
    const int* nt   = (const int*)d_in[2];
    const int* es   = (const int*)d_in[3];
    const int* ed   = (const int*)d_in[4];
    const int* et   = (const int*)d_in[5];
    const float* W1 = (const float*)d_in[6];
    const float* b1 = (const float*)d_in[7];
    const float* W2 = (const float*)d_in[8];
    const float* b2 = (const float*)d_in[9];
    // d_in[10..13] = W3,b3,W4,b4 dead (score == 1.0)
    const float* W5 = (const float*)d_in[14];
    const float* b5 = (const float*)d_in[15];

    int N = in_sizes[2];
    int M = in_sizes[3];
    int NB1 = (N + 1023) / 1024;
    int Npad = NB1 * 1024;

    char* w = (char*)d_ws;
    size_t off = 0;
    unsigned short* h2b = (unsigned short*)(w + off); off += (size_t)N * 64 * 2;
    off = (off + 255) & ~(size_t)255;
    int2* rec    = (int2*)(w + off); off += (size_t)M * 8;
    int* perm    = (int*)(w + off);  off += (size_t)N * 4;
    off = (off + 255) & ~(size_t)255;
    int* rowptr  = (int*)(w + off);  off += (size_t)Npad * 4;
    int* cursor  = (int*)(w + off);  off += (size_t)Npad * 4;
    off = (off + 255) & ~(size_t)255;
    int* cnt     = (int*)(w + off);  off += 16;
    int* cntE    = (int*)(w + off);  off += (size_t)Npad * 4;
    int* blockSum= (int*)(w + off);  off += 128 * 4;

    float* out = (float*)d_out;

    hipMemsetAsync(cnt, 0, 16 + (size_t)Npad * 4, stream);

    int gbMN = (M + 255) / 256;
    bucket_hist_kernel<<<gbMN, 256, 0, stream>>>(nt, ed, perm, cnt, cntE, N, M);

    scan1_kernel<<<NB1, 256, 0, stream>>>(cntE, rowptr, blockSum);
    finalize2_kernel<<<(N + 256) / 256, 256, 0, stream>>>(rowptr, cursor,
                                                          blockSum, N);

    int nb = (N + 127) / 128;
    int gbF = 2 * nb + gbMN;
    fused_gemm_scatter_kernel<<<gbF, 256, 0, stream>>>(
        x, perm, cnt, W1, b1, W2, b2, out, h2b,
        es, ed, et, cursor, rec, N, M, nb);

    gather_kernel<<<(N + 3) / 4, 256, 0, stream>>>(ef, rec, rowptr,
                                                   W5, b5, h2b, out, N);
}

// Round 6
// 307.975 us; speedup vs baseline: 1.5879x; 1.0065x over previous
//
#include <hip/hip_runtime.h>

// N=100000 nodes, M=800000 edges, F_IN=64, F_E=16, H=64, T_NODE=2, T_EDGE=3.
// score == softmax over singleton axis == 1.0 exactly, so h3/h4/num are dead:
//   out[n] = h1[n] + sum_{e: dst=n} ( h2[src_e] + ef_e . W5[t_e] + b5[t_e] )
//
// R6: direct-slot edge bucketing (cap 16/dst + overflow fixup) replaces the
// hist->scan->finalize->scatter chain with ONE edge pass (fused with node
// bucketing). Gather unrolled x8 (deg<=16 -> <=2 iters, 16 loads in flight).

#define CAP 16
#define OVF_CAP 32768

typedef __attribute__((ext_vector_type(8))) short short8;
typedef __attribute__((ext_vector_type(4))) float f32x4;

__device__ __forceinline__ float b2f(unsigned short u) {
    union { unsigned v; float f; } x; x.v = ((unsigned)u) << 16; return x.f;
}
__device__ __forceinline__ unsigned short f2b(float f) {
    union { float f; unsigned v; } x; x.f = f;
    unsigned u = x.v;
    unsigned r = (u + 0x7FFFu + ((u >> 16) & 1u)) >> 16;
    return (unsigned short)r;
}

// -------- fused: node-type bucketing || direct-slot edge scatter --------
__global__ __launch_bounds__(256) void bucket_scatter_kernel(
    const int* __restrict__ node_type,
    const int* __restrict__ esrc, const int* __restrict__ edst,
    const int* __restrict__ etype,
    int* __restrict__ perm, int* __restrict__ cnt,
    int* __restrict__ cnt32, int* __restrict__ ovfCnt,
    int4* __restrict__ ovf, int2* __restrict__ rec,
    int N, int M, int nodeBlocks)
{
    int tid = threadIdx.x;
    if (blockIdx.x < (unsigned)nodeBlocks) {
        // ---- node bucketing: type 0 from front, type 1 from back ----
        int i = blockIdx.x * 256 + tid;
        int lane = tid & 63;
        bool act = i < N;
        int t = act ? node_type[i] : -1;
        unsigned long long m0 = __ballot(act && (t == 0));
        unsigned long long m1 = __ballot(act && (t > 0));
        unsigned long long lt = (lane == 0) ? 0ull : ((~0ull) >> (64 - lane));
        if (act) {
            if (t == 0) {
                int cw = __popcll(m0), pre = __popcll(m0 & lt);
                int ldr = __ffsll(m0) - 1;
                int base = 0;
                if (lane == ldr) base = atomicAdd(&cnt[0], cw);
                base = __shfl(base, ldr);
                perm[base + pre] = i;
            } else {
                int cw = __popcll(m1), pre = __popcll(m1 & lt);
                int ldr = __ffsll(m1) - 1;
                int base = 0;
                if (lane == ldr) base = atomicAdd(&cnt[1], cw);
                base = __shfl(base, ldr);
                perm[N - 1 - (base + pre)] = i;
            }
        }
        return;
    }
    // ---- edge slot scatter ----
    int e = (blockIdx.x - nodeBlocks) * 256 + tid;
    if (e >= M) return;
    int d = edst[e];
    int pos = atomicAdd(&cnt32[d], 1);
    int packed = esrc[e] | (etype[e] << 20);
    if (pos < CAP) {
        rec[d * CAP + pos] = make_int2(packed, e);
    } else {
        int slot = atomicAdd(ovfCnt, 1);
        if (slot < OVF_CAP) ovf[slot] = make_int4(packed, e, d, 0);
    }
}

// ---------------- node projection: MFMA bf16, h1 -> out, h2 -> ws ----------
__global__ __launch_bounds__(256) void node_gemm_kernel(
    const float* __restrict__ x, const int* __restrict__ perm,
    const int* __restrict__ cnt,
    const float* __restrict__ W1, const float* __restrict__ b1,
    const float* __restrict__ W2, const float* __restrict__ b2,
    float* __restrict__ out, unsigned short* __restrict__ h2b,
    int N, int nb)
{
    // 72 = 64 + 8 pad: row stride 144 B -> 2-way bank alias (free)
    __shared__ __align__(16) unsigned short sx[128 * 72];
    __shared__ __align__(16) unsigned short sw[2][64 * 72];

    int tid = threadIdx.x;
    int c0 = cnt[0];
    int side = (blockIdx.x >= (unsigned)nb) ? 1 : 0;
    int b = blockIdx.x - side * nb;
    int rowbase = side ? (c0 + b * 128) : (b * 128);
    int rowend  = side ? N : c0;
    if (rowbase >= rowend) return;

    const float* W1t = W1 + side * 4096;   // [k][n] fp32
    const float* W2t = W2 + side * 4096;

#pragma unroll
    for (int j = 0; j < 4; ++j) {
        int k  = (tid >> 4) + j * 16;
        int n4 = (tid & 15) * 4;
        float4 w1v = *(const float4*)&W1t[k * 64 + n4];
        float4 w2v = *(const float4*)&W2t[k * 64 + n4];
        sw[0][(n4 + 0) * 72 + k] = f2b(w1v.x);
        sw[0][(n4 + 1) * 72 + k] = f2b(w1v.y);
        sw[0][(n4 + 2) * 72 + k] = f2b(w1v.z);
        sw[0][(n4 + 3) * 72 + k] = f2b(w1v.w);
        sw[1][(n4 + 0) * 72 + k] = f2b(w2v.x);
        sw[1][(n4 + 1) * 72 + k] = f2b(w2v.y);
        sw[1][(n4 + 2) * 72 + k] = f2b(w2v.z);
        sw[1][(n4 + 3) * 72 + k] = f2b(w2v.w);
    }

    int fr = (tid & 15) * 4;
    int ir = tid >> 4;
#pragma unroll
    for (int it = 0; it < 8; ++it) {
        int i = it * 16 + ir;
        int r = rowbase + i;
        float4 v = make_float4(0.f, 0.f, 0.f, 0.f);
        if (r < rowend) {
            int n = perm[r];
            v = *(const float4*)&x[n * 64 + fr];
        }
        ushort4 p;
        p.x = f2b(v.x); p.y = f2b(v.y); p.z = f2b(v.z); p.w = f2b(v.w);
        *(ushort4*)&sx[i * 72 + fr] = p;
    }
    __syncthreads();

    int lane = tid & 63;
    int wid  = tid >> 6;
    int q    = lane >> 4;
    int cc   = lane & 15;
    int m0   = wid * 32;

    f32x4 acc[2][2][4];
#pragma unroll
    for (int mm = 0; mm < 2; ++mm)
#pragma unroll
        for (int s = 0; s < 2; ++s)
#pragma unroll
            for (int t = 0; t < 4; ++t)
                acc[mm][s][t] = (f32x4){0.f, 0.f, 0.f, 0.f};

#pragma unroll
    for (int k0 = 0; k0 < 64; k0 += 32) {
        int ko = k0 + q * 8;
        short8 af[2];
        af[0] = *(short8*)&sx[(m0 + cc) * 72 + ko];
        af[1] = *(short8*)&sx[(m0 + 16 + cc) * 72 + ko];
        short8 bf[2][4];
#pragma unroll
        for (int mm = 0; mm < 2; ++mm)
#pragma unroll
            for (int t = 0; t < 4; ++t)
                bf[mm][t] = *(short8*)&sw[mm][(t * 16 + cc) * 72 + ko];
#pragma unroll
        for (int mm = 0; mm < 2; ++mm)
#pragma unroll
            for (int s = 0; s < 2; ++s)
#pragma unroll
                for (int t = 0; t < 4; ++t)
                    acc[mm][s][t] = __builtin_amdgcn_mfma_f32_16x16x32_bf16(
                        af[s], bf[mm][t], acc[mm][s][t], 0, 0, 0);
    }

    float bia1[4], bia2[4];
#pragma unroll
    for (int t = 0; t < 4; ++t) {
        bia1[t] = b1[side * 64 + t * 16 + cc];
        bia2[t] = b2[side * 64 + t * 16 + cc];
    }

    // C/D layout: col = lane&15, row = quad*4 + reg
#pragma unroll
    for (int s = 0; s < 2; ++s)
#pragma unroll
        for (int reg = 0; reg < 4; ++reg) {
            int rl = m0 + s * 16 + q * 4 + reg;
            int r = rowbase + rl;
            if (r < rowend) {
                int n = perm[r];
#pragma unroll
                for (int t = 0; t < 4; ++t) {
                    out[n * 64 + t * 16 + cc] = acc[0][s][t][reg] + bia1[t];
                    h2b[n * 64 + t * 16 + cc] = f2b(acc[1][s][t][reg] + bia2[t]);
                }
            }
        }
}

// ---------------- gather: one wave per dst node, deg<=CAP ----------------
// lane roles: all lanes accH += h2b[src][lane];
//   lanes 0..47: accS += (etype == lane>>4) ? ef[edge][lane&15] : 0
//   lanes 48..50: accS += (etype == lane-48) ? 1 : 0
// epilogue: out[d] += accH + 51x64 matvec of accS against [W5;b5] from LDS.
__global__ __launch_bounds__(256) void gather_kernel(
    const float* __restrict__ ef, const int2* __restrict__ rec,
    const int* __restrict__ cnt32,
    const float* __restrict__ W5, const float* __restrict__ b5,
    const unsigned short* __restrict__ h2b, float* __restrict__ out, int N)
{
    __shared__ float sW[3072 + 192];   // W5 then b5
    __shared__ float sG[4][64];

    int tid = threadIdx.x;
    for (int k = tid; k < 816; k += 256) {
        ((float4*)sW)[k] = (k < 768) ? ((const float4*)W5)[k]
                                     : ((const float4*)b5)[k - 768];
    }
    __syncthreads();

    int lane = tid & 63;
    int wid = __builtin_amdgcn_readfirstlane(tid >> 6);
    int d = blockIdx.x * 4 + wid;
    bool active = d < N;
    int deg = 0;
    if (active) deg = min(cnt32[d], CAP);
    int base = d * CAP;

    int myt = (lane < 48) ? (lane >> 4) : (lane - 48);
    int myf = lane & 15;
    float accH = 0.f, accS = 0.f;

    for (int i = 0; i < deg; i += 8) {
        int nrem = deg - i;
        int2 r[8];
#pragma unroll
        for (int j = 0; j < 8; ++j) {
            int ij = i + j;                 // clamp to valid written slots
            ij = (ij < deg) ? ij : (deg - 1);
            r[j] = rec[base + ij];
        }
        float hv[8], ev[8];
#pragma unroll
        for (int j = 0; j < 8; ++j) {
            int s = r[j].x & 0xFFFFF;
            hv[j] = b2f(h2b[(size_t)s * 64 + lane]);
            ev[j] = ef[(size_t)r[j].y * 16 + myf];
        }
#pragma unroll
        for (int j = 0; j < 8; ++j) {
            int t = (unsigned)r[j].x >> 20;
            bool ok = j < nrem;
            accH += ok ? hv[j] : 0.f;
            float v = (lane < 48) ? ev[j] : 1.0f;
            accS += (ok && (t == myt)) ? v : 0.f;
        }
    }

    sG[wid][lane] = accS;
    float rr = accH;
    const float* g = sG[wid];
#pragma unroll
    for (int j = 0; j < 48; ++j)
        rr = fmaf(g[j], sW[j * 64 + lane], rr);
#pragma unroll
    for (int t = 0; t < 3; ++t)
        rr = fmaf(g[48 + t], sW[3072 + t * 64 + lane], rr);

    if (active)
        out[(size_t)d * 64 + lane] += rr;
}

// ---------------- overflow fixup (rare: ~500 edges) ----------------
__global__ __launch_bounds__(256) void fixup_kernel(
    const float* __restrict__ ef, const int4* __restrict__ ovf,
    const int* __restrict__ ovfCnt,
    const float* __restrict__ W5, const float* __restrict__ b5,
    const unsigned short* __restrict__ h2b, float* __restrict__ out)
{
    int novf = min(*ovfCnt, OVF_CAP);
    int lane = threadIdx.x & 63;
    int gw = blockIdx.x * 4 + (threadIdx.x >> 6);
    int nw = gridDim.x * 4;
    for (int r = gw; r < novf; r += nw) {
        int4 o = ovf[r];
        int s = o.x & 0xFFFFF;
        int t = (unsigned)o.x >> 20;
        int e = o.y, d = o.z;
        float acc = b5[t * 64 + lane] + b2f(h2b[(size_t)s * 64 + lane]);
#pragma unroll
        for (int f = 0; f < 16; ++f)
            acc = fmaf(ef[(size_t)e * 16 + f], W5[t * 1024 + f * 64 + lane], acc);
        unsafeAtomicAdd(&out[(size_t)d * 64 + lane], acc);
    }
}

extern "C" void kernel_launch(void* const* d_in, const int* in_sizes, int n_in,
                              void* d_out, int out_size, void* d_ws, size_t ws_size,
                              hipStream_t stream) {
    const float* x  = (const float*)d_in[0];
    const float* ef = (const float*)d_in[1];
    const int* nt   = (const int*)d_in[2];
    const int* es   = (const int*)d_in[3];
    const int* ed   = (const int*)d_in[4];
    const int* et   = (const int*)d_in[5];
    const float* W1 = (const float*)d_in[6];
    const float* b1 = (const float*)d_in[7];
    const float* W2 = (const float*)d_in[8];
    const float* b2 = (const float*)d_in[9];
    // d_in[10..13] = W3,b3,W4,b4 dead (score == 1.0)
    const float* W5 = (const float*)d_in[14];
    const float* b5 = (const float*)d_in[15];

    int N = in_sizes[2];
    int M = in_sizes[3];

    char* w = (char*)d_ws;
    size_t off = 0;
    unsigned short* h2b = (unsigned short*)(w + off); off += (size_t)N * 64 * 2;  // 12.8 MB
    off = (off + 255) & ~(size_t)255;
    int2* rec = (int2*)(w + off); off += (size_t)N * CAP * 8;                     // 12.8 MB
    int* perm = (int*)(w + off);  off += (size_t)N * 4;
    off = (off + 255) & ~(size_t)255;
    int4* ovf = (int4*)(w + off); off += (size_t)OVF_CAP * 16;                    // 0.5 MB
    off = (off + 255) & ~(size_t)255;
    // zero block: [cnt:2 ints][ovfCnt:1][pad->64 B][cnt32: N ints]
    int* cnt    = (int*)(w + off);
    int* ovfCnt = cnt + 2;
    int* cnt32  = (int*)(w + off + 64);
    size_t zeroBytes = 64 + (size_t)N * 4;

    float* out = (float*)d_out;

    hipMemsetAsync(cnt, 0, zeroBytes, stream);

    int nodeBlocks = (N + 255) / 256;
    int edgeBlocks = (M + 255) / 256;
    bucket_scatter_kernel<<<nodeBlocks + edgeBlocks, 256, 0, stream>>>(
        nt, es, ed, et, perm, cnt, cnt32, ovfCnt, ovf, rec, N, M, nodeBlocks);

    int nb = (N + 127) / 128;
    node_gemm_kernel<<<2 * nb, 256, 0, stream>>>(x, perm, cnt, W1, b1, W2, b2,
                                                 out, h2b, N, nb);

    gather_kernel<<<(N + 3) / 4, 256, 0, stream>>>(ef, rec, cnt32,
                                                   W5, b5, h2b, out, N);

    fixup_kernel<<<32, 256, 0, stream>>>(ef, ovf, ovfCnt, W5, b5, h2b, out);
}

// Round 7
// 306.591 us; speedup vs baseline: 1.5951x; 1.0045x over previous
//
#include <hip/hip_runtime.h>

// N=100000 nodes, M=800000 edges, F_IN=64, F_E=16, H=64, T_NODE=2, T_EDGE=3.
// score == softmax over singleton axis == 1.0 exactly, so h3/h4/num are dead:
//   out[n] = h1[n] + sum_{e: dst=n} ( h2[src_e] + ef_e . W5[t_e] + b5[t_e] )
//
// R7: 3 dispatches total.
//  K1 (parity-interleaved): even blocks = MFMA node gemm computing BOTH node
//     types (no bucketing/perm), select per row; odd blocks = direct-slot edge
//     scatter with x4 ILP (4 independent atomics in flight per thread).
//  K2: gather (one wave per dst, algebraic per-type feature-sum identity) with
//     overflow-fixup tail blocks; both paths update out via unsafeAtomicAdd.

#define CAP 16
#define OVF_CAP 32768

typedef __attribute__((ext_vector_type(8))) short short8;
typedef __attribute__((ext_vector_type(4))) float f32x4;

__device__ __forceinline__ float b2f(unsigned short u) {
    union { unsigned v; float f; } x; x.v = ((unsigned)u) << 16; return x.f;
}
__device__ __forceinline__ unsigned short f2b(float f) {
    union { float f; unsigned v; } x; x.f = f;
    unsigned u = x.v;
    unsigned r = (u + 0x7FFFu + ((u >> 16) & 1u)) >> 16;
    return (unsigned short)r;
}

// ---------------- K1: gemm (even blocks) || slot scatter (odd blocks) -------
__global__ __launch_bounds__(256) void k1_gemm_scatter(
    const float* __restrict__ x, const int* __restrict__ nt,
    const float* __restrict__ W1, const float* __restrict__ b1,
    const float* __restrict__ W2, const float* __restrict__ b2,
    const int* __restrict__ esrc, const int* __restrict__ edst,
    const int* __restrict__ etype,
    int* __restrict__ cnt32, int* __restrict__ ovfCnt,
    int4* __restrict__ ovf, int2* __restrict__ rec,
    float* __restrict__ out, unsigned short* __restrict__ h2b,
    int N, int M)
{
    // 72 = 64 + 8 pad: row stride 144 B -> 2-way bank alias (free)
    __shared__ __align__(16) unsigned short sx[128 * 72];     // 18 KB
    __shared__ __align__(16) unsigned short sw[4][64 * 72];   // 36 KB
    __shared__ int snt[128];

    int tid = threadIdx.x;

    if (blockIdx.x & 1) {
        // ---------------- scatter path: 1024 edges/block, 4 per thread ------
        int e0 = (blockIdx.x >> 1) * 1024 + tid;
        int dd[4], ssrc[4], tty[4];
        bool v[4];
#pragma unroll
        for (int j = 0; j < 4; ++j) {
            int e = e0 + j * 256;
            v[j] = e < M;
            int ec = v[j] ? e : 0;
            dd[j]   = edst[ec];
            ssrc[j] = esrc[ec];
            tty[j]  = etype[ec];
        }
        int pos[4];
#pragma unroll
        for (int j = 0; j < 4; ++j)
            if (v[j]) pos[j] = atomicAdd(&cnt32[dd[j]], 1);
#pragma unroll
        for (int j = 0; j < 4; ++j) {
            if (!v[j]) continue;
            int packed = ssrc[j] | (tty[j] << 20);
            int e = e0 + j * 256;
            if (pos[j] < CAP) {
                rec[dd[j] * CAP + pos[j]] = make_int2(packed, e);
            } else {
                int slot = atomicAdd(ovfCnt, 1);
                if (slot < OVF_CAP) ovf[slot] = make_int4(packed, e, dd[j], 0);
            }
        }
        return;
    }

    // ---------------- gemm path: 128 rows x 64 h, 4 weight mats -------------
    int rowbase = (blockIdx.x >> 1) * 128;

    const float* Wm0 = W1;            // [k][n] fp32, type 0
    const float* Wm1 = W1 + 4096;     // type 1
    const float* Wm2 = W2;
    const float* Wm3 = W2 + 4096;
#pragma unroll
    for (int j = 0; j < 4; ++j) {
        int k  = (tid >> 4) + j * 16;
        int n4 = (tid & 15) * 4;
        float4 w0 = *(const float4*)&Wm0[k * 64 + n4];
        float4 w1v = *(const float4*)&Wm1[k * 64 + n4];
        float4 w2v = *(const float4*)&Wm2[k * 64 + n4];
        float4 w3 = *(const float4*)&Wm3[k * 64 + n4];
        sw[0][(n4 + 0) * 72 + k] = f2b(w0.x);
        sw[0][(n4 + 1) * 72 + k] = f2b(w0.y);
        sw[0][(n4 + 2) * 72 + k] = f2b(w0.z);
        sw[0][(n4 + 3) * 72 + k] = f2b(w0.w);
        sw[1][(n4 + 0) * 72 + k] = f2b(w1v.x);
        sw[1][(n4 + 1) * 72 + k] = f2b(w1v.y);
        sw[1][(n4 + 2) * 72 + k] = f2b(w1v.z);
        sw[1][(n4 + 3) * 72 + k] = f2b(w1v.w);
        sw[2][(n4 + 0) * 72 + k] = f2b(w2v.x);
        sw[2][(n4 + 1) * 72 + k] = f2b(w2v.y);
        sw[2][(n4 + 2) * 72 + k] = f2b(w2v.z);
        sw[2][(n4 + 3) * 72 + k] = f2b(w2v.w);
        sw[3][(n4 + 0) * 72 + k] = f2b(w3.x);
        sw[3][(n4 + 1) * 72 + k] = f2b(w3.y);
        sw[3][(n4 + 2) * 72 + k] = f2b(w3.z);
        sw[3][(n4 + 3) * 72 + k] = f2b(w3.w);
    }

    if (tid < 128) {
        int r = rowbase + tid;
        snt[tid] = (r < N) ? nt[r] : 0;
    }

    // stage x tile (contiguous rows, no perm)
    int fr = (tid & 15) * 4;
    int ir = tid >> 4;
#pragma unroll
    for (int it = 0; it < 8; ++it) {
        int i = it * 16 + ir;
        int r = rowbase + i;
        float4 v = make_float4(0.f, 0.f, 0.f, 0.f);
        if (r < N) v = *(const float4*)&x[(size_t)r * 64 + fr];
        ushort4 p;
        p.x = f2b(v.x); p.y = f2b(v.y); p.z = f2b(v.z); p.w = f2b(v.w);
        *(ushort4*)&sx[i * 72 + fr] = p;
    }
    __syncthreads();

    int lane = tid & 63;
    int wid  = tid >> 6;
    int q    = lane >> 4;
    int cc   = lane & 15;
    int m0   = wid * 32;

    f32x4 acc[4][2][4];   // [mat][s][t]
#pragma unroll
    for (int mm = 0; mm < 4; ++mm)
#pragma unroll
        for (int s = 0; s < 2; ++s)
#pragma unroll
            for (int t = 0; t < 4; ++t)
                acc[mm][s][t] = (f32x4){0.f, 0.f, 0.f, 0.f};

#pragma unroll
    for (int k0 = 0; k0 < 64; k0 += 32) {
        int ko = k0 + q * 8;
        short8 af0 = *(short8*)&sx[(m0 + cc) * 72 + ko];
        short8 af1 = *(short8*)&sx[(m0 + 16 + cc) * 72 + ko];
#pragma unroll
        for (int mm = 0; mm < 4; ++mm)
#pragma unroll
            for (int t = 0; t < 4; ++t) {
                short8 bf = *(short8*)&sw[mm][(t * 16 + cc) * 72 + ko];
                acc[mm][0][t] = __builtin_amdgcn_mfma_f32_16x16x32_bf16(
                    af0, bf, acc[mm][0][t], 0, 0, 0);
                acc[mm][1][t] = __builtin_amdgcn_mfma_f32_16x16x32_bf16(
                    af1, bf, acc[mm][1][t], 0, 0, 0);
            }
    }

    float b1v[2][4], b2v[2][4];
#pragma unroll
    for (int ty = 0; ty < 2; ++ty)
#pragma unroll
        for (int t = 0; t < 4; ++t) {
            b1v[ty][t] = b1[ty * 64 + t * 16 + cc];
            b2v[ty][t] = b2[ty * 64 + t * 16 + cc];
        }

    // C/D layout: col = lane&15, row = quad*4 + reg
#pragma unroll
    for (int s = 0; s < 2; ++s)
#pragma unroll
        for (int reg = 0; reg < 4; ++reg) {
            int rl = m0 + s * 16 + q * 4 + reg;
            int r = rowbase + rl;
            if (r < N) {
                int ty = snt[rl];
#pragma unroll
                for (int t = 0; t < 4; ++t) {
                    float v1 = (ty ? acc[1][s][t][reg] : acc[0][s][t][reg])
                               + b1v[ty][t];
                    float v2 = (ty ? acc[3][s][t][reg] : acc[2][s][t][reg])
                               + b2v[ty][t];
                    out[(size_t)r * 64 + t * 16 + cc] = v1;
                    h2b[(size_t)r * 64 + t * 16 + cc] = f2b(v2);
                }
            }
        }
}

// ---------------- K2: gather (one wave per dst) + overflow fixup tail -------
// lane roles in edge loop: all lanes accH += h2b[src][lane];
//   lanes 0..47: accS += (etype == lane>>4) ? ef[edge][lane&15] : 0
//   lanes 48..50: accS += (etype == lane-48) ? 1 : 0
// epilogue: out[d] += accH + 51x64 matvec of accS against [W5;b5] (atomic).
__global__ __launch_bounds__(256) void k2_gather(
    const float* __restrict__ ef, const int2* __restrict__ rec,
    const int* __restrict__ cnt32,
    const float* __restrict__ W5, const float* __restrict__ b5,
    const int4* __restrict__ ovf, const int* __restrict__ ovfCnt,
    const unsigned short* __restrict__ h2b, float* __restrict__ out,
    int N, int gatherBlocks, int ovfBlocks)
{
    __shared__ float sW[3072 + 192];   // W5 then b5 ([t*16+f][h], [t][h])
    __shared__ float sG[4][64];

    int tid = threadIdx.x;
    for (int k = tid; k < 816; k += 256) {
        ((float4*)sW)[k] = (k < 768) ? ((const float4*)W5)[k]
                                     : ((const float4*)b5)[k - 768];
    }
    __syncthreads();

    int lane = tid & 63;
    int wid = tid >> 6;

    if (blockIdx.x >= (unsigned)gatherBlocks) {
        // ---- overflow fixup: grid-stride waves over ovf list (rare) ----
        int novf = min(*ovfCnt, OVF_CAP);
        int gw = (blockIdx.x - gatherBlocks) * 4 + wid;
        int nw = ovfBlocks * 4;
        for (int ri = gw; ri < novf; ri += nw) {
            int4 o = ovf[ri];
            int s = o.x & 0xFFFFF;
            int t = (unsigned)o.x >> 20;
            float acc = sW[3072 + t * 64 + lane] +
                        b2f(h2b[(size_t)s * 64 + lane]);
#pragma unroll
            for (int f = 0; f < 16; ++f)
                acc = fmaf(ef[(size_t)o.y * 16 + f],
                           sW[(t * 16 + f) * 64 + lane], acc);
            unsafeAtomicAdd(&out[(size_t)o.z * 64 + lane], acc);
        }
        return;
    }

    int d = blockIdx.x * 4 + wid;
    bool active = d < N;
    int deg = 0;
    if (active) deg = min(cnt32[d], CAP);
    int base = d * CAP;

    int myt = (lane < 48) ? (lane >> 4) : (lane - 48);
    int myf = lane & 15;
    float accH = 0.f, accS = 0.f;

    for (int i = 0; i < deg; i += 8) {
        int nrem = deg - i;
        int2 r[8];
#pragma unroll
        for (int j = 0; j < 8; ++j) {
            int ij = i + j;
            ij = (ij < deg) ? ij : (deg - 1);   // clamp to written slots
            r[j] = rec[base + ij];
        }
        float hv[8], ev[8];
#pragma unroll
        for (int j = 0; j < 8; ++j) {
            int s = r[j].x & 0xFFFFF;
            hv[j] = b2f(h2b[(size_t)s * 64 + lane]);
            ev[j] = ef[(size_t)r[j].y * 16 + myf];
        }
#pragma unroll
        for (int j = 0; j < 8; ++j) {
            int t = (unsigned)r[j].x >> 20;
            bool ok = j < nrem;
            accH += ok ? hv[j] : 0.f;
            float v = (lane < 48) ? ev[j] : 1.0f;
            accS += (ok && (t == myt)) ? v : 0.f;
        }
    }

    sG[wid][lane] = accS;
    float rr = accH;
    const float* g = sG[wid];
#pragma unroll
    for (int j = 0; j < 48; ++j)
        rr = fmaf(g[j], sW[j * 64 + lane], rr);
#pragma unroll
    for (int t = 0; t < 3; ++t)
        rr = fmaf(g[48 + t], sW[3072 + t * 64 + lane], rr);

    if (active)
        unsafeAtomicAdd(&out[(size_t)d * 64 + lane], rr);
}

extern "C" void kernel_launch(void* const* d_in, const int* in_sizes, int n_in,
                              void* d_out, int out_size, void* d_ws, size_t ws_size,
                              hipStream_t stream) {
    const float* x  = (const float*)d_in[0];
    const float* ef = (const float*)d_in[1];
    const int* nt   = (const int*)d_in[2];
    const int* es   = (const int*)d_in[3];
    const int* ed   = (const int*)d_in[4];
    const int* et   = (const int*)d_in[5];
    const float* W1 = (const float*)d_in[6];
    const float* b1 = (const float*)d_in[7];
    const float* W2 = (const float*)d_in[8];
    const float* b2 = (const float*)d_in[9];
    // d_in[10..13] = W3,b3,W4,b4 dead (score == 1.0)
    const float* W5 = (const float*)d_in[14];
    const float* b5 = (const float*)d_in[15];

    int N = in_sizes[2];
    int M = in_sizes[3];

    char* w = (char*)d_ws;
    size_t off = 0;
    unsigned short* h2b = (unsigned short*)(w + off); off += (size_t)N * 64 * 2;  // 12.8 MB
    off = (off + 255) & ~(size_t)255;
    int2* rec = (int2*)(w + off); off += (size_t)N * CAP * 8;                     // 12.8 MB
    off = (off + 255) & ~(size_t)255;
    int4* ovf = (int4*)(w + off); off += (size_t)OVF_CAP * 16;                    // 0.5 MB
    off = (off + 255) & ~(size_t)255;
    // zero block: [ovfCnt:1 int][pad->64 B][cnt32: N ints]
    int* ovfCnt = (int*)(w + off);
    int* cnt32  = (int*)(w + off + 64);
    size_t zeroBytes = 64 + (size_t)N * 4;

    float* out = (float*)d_out;

    hipMemsetAsync(ovfCnt, 0, zeroBytes, stream);

    int gemmBlocks    = (N + 127) / 128;    // 782
    int scatterBlocks = (M + 1023) / 1024;  // 782
    int gb1 = 2 * max(gemmBlocks, scatterBlocks);
    k1_gemm_scatter<<<gb1, 256, 0, stream>>>(
        x, nt, W1, b1, W2, b2, es, ed, et,
        cnt32, ovfCnt, ovf, rec, out, h2b, N, M);

    int gatherBlocks = (N + 3) / 4;
    int ovfBlocks = 32;
    k2_gather<<<gatherBlocks + ovfBlocks, 256, 0, stream>>>(
        ef, rec, cnt32, W5, b5, ovf, ovfCnt, h2b, out,
        N, gatherBlocks, ovfBlocks);
}